// Round 15
// baseline (178.968 us; speedup 1.0000x reference)
//
#include <hip/hip_runtime.h>

typedef unsigned short u16;
typedef unsigned int u32;
typedef short short8 __attribute__((ext_vector_type(8)));
typedef float f32x4 __attribute__((ext_vector_type(4)));

#define B_ 4
#define N_ 2048
#define D_ 256
#define H_ 4
#define DH_ 64
#define BN_ 8192

__device__ inline float b2f(u16 u) {
    union { u32 i; float f; } v; v.i = ((u32)u) << 16; return v.f;
}
__device__ inline u16 f2b(float f) {
    union { float f; u32 i; } v; v.f = f;
    return (u16)((v.i + 0x8000u) >> 16);
}
__device__ inline u32 pkbf(float a, float b) {
    union { float f; u32 i; } ua, ub; ua.f = a; ub.f = b;
    return __builtin_amdgcn_perm(ub.i + 0x8000u, ua.i + 0x8000u, 0x07060302u);
}
__device__ inline f32x4 mfma16(short8 a, short8 b, f32x4 c) {
    return __builtin_amdgcn_mfma_f32_16x16x32_bf16(a, b, c, 0, 0, 0);
}

// -------- MFMA GEMM body, block=128x128, wave=64x64 (qkv) -------------------
__device__ __forceinline__ void gemm_body(
    int bx, int by, int tid,
    const u16* __restrict__ A, const u16* __restrict__ BT,
    const float* __restrict__ bias, void* __restrict__ Cout,
    int Ntot)
{
    const int wave = tid >> 6, lane = tid & 63;
    const int ln15 = lane & 15, quad = lane >> 4;
    const int m0 = bx * 128 + (wave & 1) * 64;
    const int n0 = by * 128 + (wave >> 1) * 64;

    const f32x4 zero = {0.f, 0.f, 0.f, 0.f};
    f32x4 acc[4][4];
    #pragma unroll
    for (int i = 0; i < 4; ++i)
        #pragma unroll
        for (int j = 0; j < 4; ++j) acc[i][j] = zero;

    #pragma unroll
    for (int k0 = 0; k0 < 256; k0 += 32) {
        const int koff = k0 + quad * 8;
        short8 a[4], b[4];
        #pragma unroll
        for (int i = 0; i < 4; ++i)
            a[i] = *(const short8*)(A + (size_t)(m0 + i * 16 + ln15) * 256 + koff);
        #pragma unroll
        for (int j = 0; j < 4; ++j)
            b[j] = *(const short8*)(BT + (size_t)(n0 + j * 16 + ln15) * 256 + koff);
        #pragma unroll
        for (int i = 0; i < 4; ++i)
            #pragma unroll
            for (int j = 0; j < 4; ++j)
                acc[i][j] = mfma16(a[i], b[j], acc[i][j]);
    }

    #pragma unroll
    for (int i = 0; i < 4; ++i) {
        const int r = m0 + i * 16 + quad * 4;
        #pragma unroll
        for (int j = 0; j < 4; ++j) {
            const int c = n0 + j * 16 + ln15;
            const float bv = bias[c];
            #pragma unroll
            for (int rg = 0; rg < 4; ++rg) {
                const size_t idx = (size_t)(r + rg) * Ntot + c;
                ((u16*)Cout)[idx] = f2b(acc[i][j][rg] + bv);
            }
        }
    }
}

// -------- thin MFMA GEMM body, block=64x64, wave=32x32 (gate, Ntot=256) -----
__device__ __forceinline__ void gemm_thin_body(
    int bx, int by, int tid,
    const u16* __restrict__ A, const u16* __restrict__ BT,
    const float* __restrict__ bias, u16* __restrict__ Cout)
{
    const int wave = tid >> 6, lane = tid & 63;
    const int ln15 = lane & 15, quad = lane >> 4;
    const int m0 = bx * 64 + (wave & 1) * 32;
    const int n0 = by * 64 + (wave >> 1) * 32;

    const f32x4 zero = {0.f, 0.f, 0.f, 0.f};
    f32x4 acc[2][2];
    #pragma unroll
    for (int i = 0; i < 2; ++i)
        #pragma unroll
        for (int j = 0; j < 2; ++j) acc[i][j] = zero;

    #pragma unroll
    for (int k0 = 0; k0 < 256; k0 += 32) {
        const int koff = k0 + quad * 8;
        short8 a[2], b[2];
        #pragma unroll
        for (int i = 0; i < 2; ++i)
            a[i] = *(const short8*)(A + (size_t)(m0 + i * 16 + ln15) * 256 + koff);
        #pragma unroll
        for (int j = 0; j < 2; ++j)
            b[j] = *(const short8*)(BT + (size_t)(n0 + j * 16 + ln15) * 256 + koff);
        #pragma unroll
        for (int i = 0; i < 2; ++i)
            #pragma unroll
            for (int j = 0; j < 2; ++j)
                acc[i][j] = mfma16(a[i], b[j], acc[i][j]);
    }

    #pragma unroll
    for (int i = 0; i < 2; ++i) {
        const int r = m0 + i * 16 + quad * 4;
        #pragma unroll
        for (int j = 0; j < 2; ++j) {
            const int c = n0 + j * 16 + ln15;
            const float bv = bias[c];
            #pragma unroll
            for (int rg = 0; rg < 4; ++rg) {
                float v = acc[i][j][rg] + bv;
                Cout[(size_t)(r + rg) * 256 + c] = f2b(1.0f / (1.0f + __expf(-v)));
            }
        }
    }
}

__global__ __launch_bounds__(256) void gemm_ep(
    const u16* __restrict__ A, const u16* __restrict__ BT,
    const float* __restrict__ bias, void* __restrict__ Cout, int Ntot)
{
    gemm_body(blockIdx.x, blockIdx.y, threadIdx.x, A, BT, bias, Cout, Ntot);
}

// -------- out GEMM with on-the-fly split-K combine of attention partials ----
// A-frag built as y = (o0+o1)/(l0+l1) cast to bf16; C = x + gate*(y@W + bias)
__global__ __launch_bounds__(256) void out_gemm_k(
    const float* __restrict__ o0, const float* __restrict__ o1,
    const float* __restrict__ lv0, const float* __restrict__ lv1,
    const u16* __restrict__ BT, const float* __restrict__ bias,
    float* __restrict__ Cout, const float* __restrict__ xin,
    const u16* __restrict__ gate)
{
    const int tid = threadIdx.x;
    const int wave = tid >> 6, lane = tid & 63;
    const int ln15 = lane & 15, quad = lane >> 4;
    const int m0 = blockIdx.x * 64 + (wave & 1) * 32;
    const int n0 = blockIdx.y * 64 + (wave >> 1) * 32;

    const f32x4 zero = {0.f, 0.f, 0.f, 0.f};
    f32x4 acc[2][2];
    #pragma unroll
    for (int i = 0; i < 2; ++i)
        #pragma unroll
        for (int j = 0; j < 2; ++j) acc[i][j] = zero;

    #pragma unroll
    for (int k0 = 0; k0 < 256; k0 += 32) {
        const int koff = k0 + quad * 8;
        const int head = k0 >> 6;        // quad*8 <= 24, k0%64 in {0,32}
        short8 a[2], b[2];
        #pragma unroll
        for (int i = 0; i < 2; ++i) {
            const int m = m0 + i * 16 + ln15;
            const float* p0 = o0 + (size_t)m * 256 + koff;
            const float* p1 = o1 + (size_t)m * 256 + koff;
            float4 a0 = *(const float4*)p0, a1 = *(const float4*)(p0 + 4);
            float4 c0 = *(const float4*)p1, c1 = *(const float4*)(p1 + 4);
            const int il = ((m >> 11) * 4 + head) * 2048 + (m & 2047);
            const float rl = 1.0f / (lv0[il] + lv1[il]);
            union { u32 u[4]; short8 s; } r;
            r.u[0] = pkbf((a0.x + c0.x) * rl, (a0.y + c0.y) * rl);
            r.u[1] = pkbf((a0.z + c0.z) * rl, (a0.w + c0.w) * rl);
            r.u[2] = pkbf((a1.x + c1.x) * rl, (a1.y + c1.y) * rl);
            r.u[3] = pkbf((a1.z + c1.z) * rl, (a1.w + c1.w) * rl);
            a[i] = r.s;
        }
        #pragma unroll
        for (int j = 0; j < 2; ++j)
            b[j] = *(const short8*)(BT + (size_t)(n0 + j * 16 + ln15) * 256 + koff);
        #pragma unroll
        for (int i = 0; i < 2; ++i)
            #pragma unroll
            for (int j = 0; j < 2; ++j)
                acc[i][j] = mfma16(a[i], b[j], acc[i][j]);
    }

    #pragma unroll
    for (int i = 0; i < 2; ++i) {
        const int r = m0 + i * 16 + quad * 4;
        #pragma unroll
        for (int j = 0; j < 2; ++j) {
            const int c = n0 + j * 16 + ln15;
            const float bv = bias[c];
            #pragma unroll
            for (int rg = 0; rg < 4; ++rg) {
                const size_t idx = (size_t)(r + rg) * 256 + c;
                float v = acc[i][j][rg] + bv;
                Cout[idx] = xin[idx] + b2f(gate[idx]) * v;
            }
        }
    }
}

// -------- fused: zc-RMSNorm (blocks 0..2047) + weight transpose (2048..3071)
__global__ __launch_bounds__(256) void norm_transw_k(
    const float* __restrict__ x, const float* __restrict__ g, u16* __restrict__ h,
    const float* __restrict__ wqkv, const float* __restrict__ wout,
    const float* __restrict__ wgate,
    u16* __restrict__ wqkvT, u16* __restrict__ woutT, u16* __restrict__ wgateT)
{
    if (blockIdx.x < 2048) {
        const int wave = threadIdx.x >> 6, lane = threadIdx.x & 63;
        const int t = blockIdx.x * 4 + wave;
        const float4 u = *(const float4*)(x + (size_t)t * D_ + lane * 4);
        float s  = u.x + u.y + u.z + u.w;
        float s2 = u.x * u.x + u.y * u.y + u.z * u.z + u.w * u.w;
        #pragma unroll
        for (int m = 1; m < 64; m <<= 1) {
            s  += __shfl_xor(s, m);
            s2 += __shfl_xor(s2, m);
        }
        float mean = s * (1.0f / D_);
        float var  = s2 * (1.0f / D_) - mean * mean;
        float rinv = rsqrtf(var + 1e-8f);
        const float4 gv = *(const float4*)(g + lane * 4);
        uint2 o;
        o.x = pkbf((u.x - mean) * rinv * gv.x, (u.y - mean) * rinv * gv.y);
        o.y = pkbf((u.z - mean) * rinv * gv.z, (u.w - mean) * rinv * gv.w);
        *(uint2*)(h + (size_t)t * D_ + lane * 4) = o;
    } else {
        int idx = (blockIdx.x - 2048) * 256 + threadIdx.x;
        if (idx < 768 * 256) {
            int nn = idx >> 8, kk = idx & 255;
            wqkvT[idx] = f2b(wqkv[kk * 768 + nn]);
        }
        idx -= 768 * 256;
        if (idx >= 0 && idx < 256 * 256) {
            int nn = idx >> 8, kk = idx & 255;
            woutT[idx]  = f2b(wout[kk * 256 + nn]);
            wgateT[idx] = f2b(wgate[kk * 256 + nn]);
        }
    }
}

// -------- fused: RoPE x4 (0..1023) + V-transpose (1024..1535)
//          + gate GEMM thin (1536..2047)
#define QSCALE 0.18033688f   // 0.125 * log2(e)
__global__ __launch_bounds__(256) void rope_vt_gate_k(
    const u16* __restrict__ qkv, const float* __restrict__ freqs,
    u16* __restrict__ Q, u16* __restrict__ K, u16* __restrict__ VT,
    const u16* __restrict__ h, const u16* __restrict__ wgateT,
    const float* __restrict__ b_gate, u16* __restrict__ gatb)
{
    __shared__ __align__(16) u16 tile[64 * 65];
    const int blk = blockIdx.x;
    if (blk < 1024) {
        const int idx = blk * 256 + threadIdx.x;
        const int t = idx >> 5, rem = idx & 31;
        const int hh = rem >> 3, s8 = rem & 7;
        const int b = t >> 11, n = t & 2047;

        const float4 f0 = *(const float4*)(freqs + (size_t)n * 64 + s8 * 8);
        const float4 f1 = *(const float4*)(freqs + (size_t)n * 64 + s8 * 8 + 4);

        const u16* qp = qkv + (size_t)t * 768 + hh * 64 + s8 * 8;
        const uint4 qv = *(const uint4*)qp;
        const uint4 kv = *(const uint4*)(qp + 256);

        const size_t off = ((size_t)(b * H_ + hh) * N_ + n) * DH_ + s8 * 8;
        uint4 qo, ko;
        {
            float q0 = b2f((u16)(qv.x & 0xffff)), q1 = b2f((u16)(qv.x >> 16));
            float k0 = b2f((u16)(kv.x & 0xffff)), k1 = b2f((u16)(kv.x >> 16));
            qo.x = pkbf((q0 * f0.x - q1 * f0.y) * QSCALE, (q0 * f0.y + q1 * f0.x) * QSCALE);
            ko.x = pkbf(k0 * f0.x - k1 * f0.y, k0 * f0.y + k1 * f0.x);
        }
        {
            float q0 = b2f((u16)(qv.y & 0xffff)), q1 = b2f((u16)(qv.y >> 16));
            float k0 = b2f((u16)(kv.y & 0xffff)), k1 = b2f((u16)(kv.y >> 16));
            qo.y = pkbf((q0 * f0.z - q1 * f0.w) * QSCALE, (q0 * f0.w + q1 * f0.z) * QSCALE);
            ko.y = pkbf(k0 * f0.z - k1 * f0.w, k0 * f0.w + k1 * f0.z);
        }
        {
            float q0 = b2f((u16)(qv.z & 0xffff)), q1 = b2f((u16)(qv.z >> 16));
            float k0 = b2f((u16)(kv.z & 0xffff)), k1 = b2f((u16)(kv.z >> 16));
            qo.z = pkbf((q0 * f1.x - q1 * f1.y) * QSCALE, (q0 * f1.y + q1 * f1.x) * QSCALE);
            ko.z = pkbf(k0 * f1.x - k1 * f1.y, k0 * f1.y + k1 * f1.x);
        }
        {
            float q0 = b2f((u16)(qv.w & 0xffff)), q1 = b2f((u16)(qv.w >> 16));
            float k0 = b2f((u16)(kv.w & 0xffff)), k1 = b2f((u16)(kv.w >> 16));
            qo.w = pkbf((q0 * f1.z - q1 * f1.w) * QSCALE, (q0 * f1.w + q1 * f1.z) * QSCALE);
            ko.w = pkbf(k0 * f1.z - k1 * f1.w, k0 * f1.w + k1 * f1.z);
        }
        *(uint4*)(Q + off) = qo;
        *(uint4*)(K + off) = ko;
    } else if (blk < 1536) {
        const int id2 = blk - 1024;
        const int bh = id2 & 15;
        const int n0 = (id2 >> 4) * 64;
        const int b = bh >> 2, hh = bh & 3;
        #pragma unroll
        for (int rep = 0; rep < 16; ++rep) {
            int idx = rep * 256 + threadIdx.x;
            int nl = idx >> 6, dh = idx & 63;
            tile[dh * 65 + nl] = qkv[(size_t)(b * N_ + n0 + nl) * 768 + 512 + hh * 64 + dh];
        }
        __syncthreads();
        #pragma unroll
        for (int rep = 0; rep < 16; ++rep) {
            int idx = rep * 256 + threadIdx.x;
            int dh = idx >> 6, nl = idx & 63;
            VT[((size_t)bh * 64 + dh) * N_ + n0 + nl] = tile[dh * 65 + nl];
        }
    } else {
        const int id3 = blk - 1536;            // [0,512): thin gate GEMM
        gemm_thin_body(id3 & 127, id3 >> 7, threadIdx.x, h, wgateT, b_gate, gatb);
    }
}

// -------- flash attention: wave = 64 queries, split-K=2 across blocks -------
// Block = 4 waves x 64 q = 256 queries sharing one staged 64-key chunk;
// K/V frag reads amortized over 4 q-subtiles (LDS bytes/query 1.5->0.56 KB).
// Grid 256 = 16 bh x 8 qb x 2 ksplit (1 block/CU). Max-free softmax ->
// partials are plain sums: f32 partial O (yt layout) + partial l, combined
// in out_gemm_k. XCD swizzle: id&7 -> 1 MB K/V per XCD L2.
__global__ __launch_bounds__(256, 1) void attn_k(
    const u16* __restrict__ Q, const u16* __restrict__ K,
    const u16* __restrict__ VT, float* __restrict__ opart,
    float* __restrict__ lvp)
{
    __shared__ __align__(16) u16 Ks[2][64][72];
    __shared__ __align__(16) u16 Vs[2][64][72];
    __shared__ __align__(16) u16 Pb[4][64 * 72];
    const int tid = threadIdx.x;
    const int wave = tid >> 6, lane = tid & 63;
    const int ln15 = lane & 15, quad = lane >> 4;
    const int id = blockIdx.x;
    const int bh = ((id & 7) << 1) | ((id >> 3) & 1);
    const int rest = id >> 4;                 // 0..15
    const int qb = rest & 7, ks = rest >> 3;
    const int q0w = qb * 256 + wave * 64;

    const u16* Qh = Q + (size_t)bh * N_ * DH_;
    const u16* Kh = K + (size_t)bh * N_ * DH_;
    const u16* Vh = VT + (size_t)bh * DH_ * N_;

    short8 bq[4][2];
    #pragma unroll
    for (int qs = 0; qs < 4; ++qs) {
        const u16* qp = Qh + (size_t)(q0w + qs * 16 + ln15) * DH_;
        bq[qs][0] = *(const short8*)(qp + quad * 8);
        bq[qs][1] = *(const short8*)(qp + 32 + quad * 8);
    }

    const f32x4 zero = {0.f, 0.f, 0.f, 0.f};
    f32x4 o[4][4];                      // o[j=dh-subtile][qs]
    #pragma unroll
    for (int j = 0; j < 4; ++j)
        #pragma unroll
        for (int qs = 0; qs < 4; ++qs) o[j][qs] = zero;
    float lv[4] = {0.f, 0.f, 0.f, 0.f};
    u16* Pw = Pb[wave];

    const int kbeg = ks * (N_ / 2);
    const int srow = tid >> 2, sq4 = tid & 3;

    {
        uint4 k0 = *(const uint4*)(Kh + (size_t)(kbeg + srow) * DH_ + sq4 * 8);
        uint4 k1 = *(const uint4*)(Kh + (size_t)(kbeg + srow) * DH_ + (sq4 + 4) * 8);
        uint4 v0 = *(const uint4*)(Vh + (size_t)srow * N_ + kbeg + sq4 * 8);
        uint4 v1 = *(const uint4*)(Vh + (size_t)srow * N_ + kbeg + (sq4 + 4) * 8);
        *(uint4*)&Ks[0][srow][sq4 * 8] = k0;
        *(uint4*)&Ks[0][srow][(sq4 + 4) * 8] = k1;
        *(uint4*)&Vs[0][srow][sq4 * 8] = v0;
        *(uint4*)&Vs[0][srow][(sq4 + 4) * 8] = v1;
    }
    __syncthreads();

    int p = 0;
    for (int c = 0; c < 16; ++c) {
        const int ktn = kbeg + (c + 1) * 64;
        uint4 k0, k1, v0, v1;
        const bool more = (c + 1 < 16);
        if (more) {
            k0 = *(const uint4*)(Kh + (size_t)(ktn + srow) * DH_ + sq4 * 8);
            k1 = *(const uint4*)(Kh + (size_t)(ktn + srow) * DH_ + (sq4 + 4) * 8);
            v0 = *(const uint4*)(Vh + (size_t)srow * N_ + ktn + sq4 * 8);
            v1 = *(const uint4*)(Vh + (size_t)srow * N_ + ktn + (sq4 + 4) * 8);
        }

        // ---- S phase: K-frags loaded once, reused over 4 q-subtiles ----
        short8 ka[4][2];
        #pragma unroll
        for (int c4 = 0; c4 < 4; ++c4) {
            ka[c4][0] = *(const short8*)&Ks[p][c4 * 16 + ln15][quad * 8];
            ka[c4][1] = *(const short8*)&Ks[p][c4 * 16 + ln15][32 + quad * 8];
        }
        #pragma unroll
        for (int qs = 0; qs < 4; ++qs) {
            f32x4 st[4];
            #pragma unroll
            for (int c4 = 0; c4 < 4; ++c4) {
                st[c4] = mfma16(ka[c4][0], bq[qs][0], zero);
                st[c4] = mfma16(ka[c4][1], bq[qs][1], st[c4]);
            }
            float rs = 0.f;
            #pragma unroll
            for (int c4 = 0; c4 < 4; ++c4) {
                f32x4 pr;
                #pragma unroll
                for (int r = 0; r < 4; ++r) { pr[r] = exp2f(st[c4][r]); rs += pr[r]; }
                uint2 w;
                w.x = pkbf(pr[0], pr[1]);
                w.y = pkbf(pr[2], pr[3]);
                *(uint2*)(Pw + (qs * 16 + ln15) * 72 + c4 * 16 + quad * 4) = w;
            }
            lv[qs] += rs;
        }
        asm volatile("s_waitcnt lgkmcnt(0)" ::: "memory");

        // ---- PV phase: V-frags loaded once, reused over 4 q-subtiles ----
        short8 va[4][2];
        #pragma unroll
        for (int j = 0; j < 4; ++j) {
            va[j][0] = *(const short8*)&Vs[p][j * 16 + ln15][quad * 8];
            va[j][1] = *(const short8*)&Vs[p][j * 16 + ln15][32 + quad * 8];
        }
        #pragma unroll
        for (int qs = 0; qs < 4; ++qs) {
            const short8 bp0 = *(const short8*)(Pw + (qs * 16 + ln15) * 72 + quad * 8);
            const short8 bp1 = *(const short8*)(Pw + (qs * 16 + ln15) * 72 + 32 + quad * 8);
            #pragma unroll
            for (int j = 0; j < 4; ++j) {
                o[j][qs] = mfma16(va[j][0], bp0, o[j][qs]);
                o[j][qs] = mfma16(va[j][1], bp1, o[j][qs]);
            }
        }

        if (more) {
            *(uint4*)&Ks[p ^ 1][srow][sq4 * 8] = k0;
            *(uint4*)&Ks[p ^ 1][srow][(sq4 + 4) * 8] = k1;
            *(uint4*)&Vs[p ^ 1][srow][sq4 * 8] = v0;
            *(uint4*)&Vs[p ^ 1][srow][(sq4 + 4) * 8] = v1;
        }
        __syncthreads();
        p ^= 1;
    }

    #pragma unroll
    for (int qs = 0; qs < 4; ++qs) {
        lv[qs] += __shfl_xor(lv[qs], 16);
        lv[qs] += __shfl_xor(lv[qs], 32);
    }
    const int b = bh >> 2, h = bh & 3;
    if (quad == 0) {
        #pragma unroll
        for (int qs = 0; qs < 4; ++qs)
            lvp[(size_t)ks * 32768 + bh * 2048 + q0w + qs * 16 + ln15] = lv[qs];
    }
    float* op = opart + (size_t)ks * BN_ * D_;
    #pragma unroll
    for (int qs = 0; qs < 4; ++qs) {
        const size_t tok = (size_t)b * N_ + q0w + qs * 16 + ln15;
        #pragma unroll
        for (int j = 0; j < 4; ++j) {
            float4 w;
            w.x = o[j][qs][0]; w.y = o[j][qs][1];
            w.z = o[j][qs][2]; w.w = o[j][qs][3];
            *(float4*)(op + tok * D_ + h * 64 + j * 16 + quad * 4) = w;
        }
    }
}

extern "C" void kernel_launch(void* const* d_in, const int* in_sizes, int n_in,
                              void* d_out, int out_size, void* d_ws, size_t ws_size,
                              hipStream_t stream) {
    const float* x      = (const float*)d_in[0];
    const float* freqs  = (const float*)d_in[1];
    const float* g      = (const float*)d_in[2];
    const float* w_qkv  = (const float*)d_in[3];
    const float* b_qkv  = (const float*)d_in[4];
    const float* w_out  = (const float*)d_in[5];
    const float* b_out  = (const float*)d_in[6];
    const float* w_gate = (const float*)d_in[7];
    const float* b_gate = (const float*)d_in[8];
    float* out = (float*)d_out;          // f32 output (round-5 post-mortem)

    char* ws = (char*)d_ws;
    size_t off = 0;
    auto carveB = [&](size_t bytes) -> char* {
        char* p = ws + off;
        off += (bytes + 255) & ~(size_t)255;
        return p;
    };
    u16* h      = (u16*)carveB((size_t)BN_ * D_ * 2);
    u16* qkv    = (u16*)carveB((size_t)BN_ * 768 * 2);
    u16* Qb     = (u16*)carveB((size_t)BN_ * D_ * 2);
    u16* Kb     = (u16*)carveB((size_t)BN_ * D_ * 2);
    u16* VT     = (u16*)carveB((size_t)BN_ * D_ * 2);
    u16* gatb   = (u16*)carveB((size_t)BN_ * D_ * 2);
    u16* wqkvT  = (u16*)carveB((size_t)768 * 256 * 2);
    u16* woutT  = (u16*)carveB((size_t)256 * 256 * 2);
    u16* wgateT = (u16*)carveB((size_t)256 * 256 * 2);
    float* opart = (float*)carveB((size_t)2 * BN_ * D_ * 4);   // 16 MB
    float* lvp   = (float*)carveB((size_t)2 * 16 * N_ * 4);    // 256 KB

    hipLaunchKernelGGL(norm_transw_k, dim3(3072), dim3(256), 0, stream,
                       x, g, h, w_qkv, w_out, w_gate, wqkvT, woutT, wgateT);
    hipLaunchKernelGGL(gemm_ep, dim3(BN_ / 128, 6), dim3(256), 0, stream,
                       h, wqkvT, b_qkv, (void*)qkv, 768);
    hipLaunchKernelGGL(rope_vt_gate_k, dim3(2048), dim3(256), 0, stream,
                       qkv, freqs, Qb, Kb, VT, h, wgateT, b_gate, gatb);
    hipLaunchKernelGGL(attn_k, dim3(256), dim3(256), 0, stream,
                       Qb, Kb, VT, opart, lvp);
    hipLaunchKernelGGL(out_gemm_k, dim3(BN_ / 64, 4), dim3(256), 0, stream,
                       opart, opart + (size_t)BN_ * D_, lvp, lvp + 32768,
                       woutT, b_out, out, x, gatb);
}